// Round 13
// baseline (32.721 us; speedup 1.0000x reference)
//
#include <hip/hip_runtime.h>

// out[b,s,h,w] = sum_t input[b,s,t,h,w] * weight[t, h%8, w%8]   (h,w < 256; else 0)
// output[b, s*1024 + i*32 + j, q*16 + p] = out[b,s, 8i+p, 8j+q]   i,j in [0,32), p,q in [0,16)
//
// Round-13: R12 structure, finer again: 2048 blocks x 256 threads, block
// (b,s,g) g in 0..63 owns image rows [4g,4g+4) disjointly. launch_bounds(256,5)
// -> 5 blocks/CU, 20 waves/CU (R12: 4 blocks, 16 waves): more phase desync,
// smaller barrier payloads.
// Phase 1 (identical schedule to R10/R12): one f4 slot/thread, 16-deep batched
// 1KB wave bursts + sched_barrier fence, FMA, LDS commit.
// Phase 2: the 4 owned rows = one 16B p-quad at pp0 = (g&1)*4. Per (j,q2) unit:
// one vertical LDS gather, two 16B stores:
//   A: window-row i1 = g>>1,  p = pp0..pp0+3
//   B: window-row i1-1,       p = pp0+8..   (skip if i1==0)
// Col padding via zeroed LDS halo cols; row padding (i=31, p>=8) by g==63.

namespace {

constexpr int TT   = 16;
constexpr int LDSW = 268;   // 264 cols + 4 pad

__global__ __launch_bounds__(256, 5) void meas_kernel(
    const float* __restrict__ in, const float* __restrict__ wt,
    float* __restrict__ out)
{
    __shared__ float tile[4 * LDSW];
    __shared__ float wlds[TT * 64];

    const int tid = threadIdx.x;
    for (int idx = tid; idx < TT * 64; idx += 256) wlds[idx] = wt[idx];

    // zero halo cols 256..263 (c4 slots 64,65) of the 4 tile rows
    if (tid < 8) {
        const int r  = tid >> 1;
        const int c4 = 64 + (tid & 1);
        *reinterpret_cast<float4*>(&tile[r * LDSW + c4 * 4]) =
            make_float4(0.f, 0.f, 0.f, 0.f);
    }

    // XCD swizzle: 2048 blocks, 8 XCDs -> 256 logical blocks (one b) per XCD;
    // g-neighbors (output line partners) adjacent -> co-XCD, co-time.
    const int bid = (blockIdx.x & 7) * 256 + (blockIdx.x >> 3);
    const int g = bid & 63;
    const int s = (bid >> 6) & 3;
    const int b = bid >> 8;

    const float* __restrict__ inp = in + (size_t)(b * 4 + s) * TT * 65536;
    float* __restrict__ outb = out + ((size_t)b * 4096 + (size_t)s * 1024) * 256;

    // row padding (i=31, p>=8) <- image rows 256..263 = zeros: g==63 owns
    if (g == 63) {
        const float4 z4 = make_float4(0.f, 0.f, 0.f, 0.f);
#pragma unroll
        for (int m2 = 0; m2 < 4; ++m2) {
            const int u = m2 * 256 + tid;        // 0..1023
            const int j = u >> 5, e = u & 31;
            const int q2 = e >> 1, p0 = 8 + (e & 1) * 4;
            *reinterpret_cast<float4*>(outb + (size_t)(992 + j) * 256 + q2 * 16 + p0) = z4;
        }
    }

    __syncthreads();   // weights + halo zeros visible

    // ---- Phase 1: t-sum of rows [4g, 4g+4) into LDS ----
    // r = tid>>6 (wave-uniform), lane c = tid&63 -> w = 4c: per t one aligned
    // contiguous 1KB wave burst. No bounds checks.
    {
        const int r = tid >> 6;       // 0..3
        const int c = tid & 63;
        const int h = g * 4 + r;
        const int w = c * 4;
        const float* gp = inp + h * 256 + w;

        // 1) issue all 16 strided 1KB bursts back-to-back (16KB/wave in flight)
        float4 v[TT];
#pragma unroll
        for (int t = 0; t < TT; ++t)
            v[t] = *reinterpret_cast<const float4*>(gp + t * 65536);

        __builtin_amdgcn_sched_barrier(0);   // no FMA hoisted above

        // 2) FMA against LDS-resident weights
        const float* wrow = &wlds[(h & 7) * 8 + (w & 7)];
        float4 acc = make_float4(0.f, 0.f, 0.f, 0.f);
#pragma unroll
        for (int t = 0; t < TT; ++t) {
            const float4 wv = *reinterpret_cast<const float4*>(wrow + t * 64);
            acc.x += v[t].x * wv.x;
            acc.y += v[t].y * wv.y;
            acc.z += v[t].z * wv.z;
            acc.w += v[t].w * wv.w;
        }
        *reinterpret_cast<float4*>(&tile[r * LDSW + w]) = acc;
    }

    __syncthreads();

    // ---- Phase 2: 512 (j,q2) units, 2 per thread; 2 stores per unit ----
    const int i1  = g >> 1;
    const int pp0 = (g & 1) * 4;
#pragma unroll
    for (int m2 = 0; m2 < 2; ++m2) {
        const int u  = m2 * 256 + tid;   // 0..511
        const int j  = u >> 4;           // 0..31
        const int q2 = u & 15;           // 0..15
        const float* src = &tile[j * 8 + q2];
        const float4 a4 = make_float4(src[0], src[LDSW], src[2 * LDSW], src[3 * LDSW]);

        // membership A: window-row i1, p = pp0..pp0+3
        *reinterpret_cast<float4*>(outb + (size_t)(i1 * 32 + j) * 256 + q2 * 16 + pp0) = a4;
        // membership B: window-row i1-1, p = pp0+8..
        if (i1 > 0)
            *reinterpret_cast<float4*>(outb + (size_t)((i1 - 1) * 32 + j) * 256 + q2 * 16 + pp0 + 8) = a4;
    }
}

} // namespace

extern "C" void kernel_launch(void* const* d_in, const int* in_sizes, int n_in,
                              void* d_out, int out_size, void* d_ws, size_t ws_size,
                              hipStream_t stream) {
    const float* in = (const float*)d_in[0];
    const float* wt = (const float*)d_in[1];
    float* out      = (float*)d_out;
    hipLaunchKernelGGL(meas_kernel, dim3(2048), dim3(256), 0, stream, in, wt, out);
}